// Round 15
// baseline (581.739 us; speedup 1.0000x reference)
//
#include <hip/hip_runtime.h>
#include <hip/hip_bf16.h>
#include <hip/hip_fp8.h>
#include <stdint.h>

// Problem constants (fixed by reference): B=2048, D=256, Vg=2, Vt=4 (only j<2 used), T=0.2
#define TB 2048
#define TD 256

// ABLATION ROUND 2: which phase of main costs ~13 unexplained us?
// V0=full anchor  V1=no-exp  V2=B-loads hoisted (no per-cgl load)  V4=unroll 1
#define REP_PREP 32
#define REP_MAIN 8

typedef long long                                         fp8x8;   // 8 fp8 = 2 VGPR
typedef __attribute__((ext_vector_type(8)))  int          int8v;   // 32 fp8 = 8 VGPR
typedef __attribute__((ext_vector_type(16))) float        f32x16;

union frag32 { fp8x8 g[4]; int8v v; };   // 4 x 8B granules = one 32x32x64 operand

#define SQRT5 2.23606797749979f
#define SCALE1 0x7F               // E8M0: 2^(127-127) = 1.0

// ---------------------------------------------------------------------------
// Kernel 1: prep (== R10), REP-looped to pin its standalone cost (P = dur/32)
// ---------------------------------------------------------------------------
__global__ __launch_bounds__(256) void nnclr_prep(const float* __restrict__ proj,
                                                  const float* __restrict__ pred,
                                                  unsigned char* __restrict__ pq2) {
    const int grp = blockIdx.x, v = blockIdx.y, t = threadIdx.x;
    __shared__ float rowbuf[32][260];
    __shared__ float scales[32];

    for (int rep = 0; rep < REP_PREP; ++rep) {
        asm volatile("" ::: "memory");
        #pragma unroll
        for (int it = 0; it < 8; ++it) {
            const int f = it * 256 + t;
            const int m = f >> 6, q = f & 63;
            const int b = grp * 32 + m;
            const float4* src = (v < 2) ? (const float4*)(proj + ((size_t)b * 2 + v) * TD)
                                        : (const float4*)(pred + ((size_t)b * 4 + (v - 2)) * TD);
            *(float4*)&rowbuf[m][q * 4] = src[q];
        }
        __syncthreads();
        {
            const int row = t >> 3, l8 = t & 7;
            float ss = 0.f;
            #pragma unroll
            for (int n = 0; n < 32; ++n) { const float y = rowbuf[row][l8 + 8 * n]; ss += y * y; }
            ss += __shfl_xor(ss, 1, 64);
            ss += __shfl_xor(ss, 2, 64);
            ss += __shfl_xor(ss, 4, 64);
            if (l8 == 0) scales[row] = SQRT5 / fmaxf(sqrtf(ss), 1e-12f);
        }
        __syncthreads();
        unsigned int* dst32 = (unsigned int*)(pq2 + (size_t)(v * 64 + grp) * 8192);
        #pragma unroll
        for (int it = 0; it < 8; ++it) {
            const int u = it * 256 + t;
            const int m = u >> 6, col = (u >> 1) & 31, e4 = u & 1;
            const float sc = scales[col];
            unsigned int w = 0;
            #pragma unroll
            for (int i = 0; i < 4; ++i) {
                const float y = rowbuf[col][m * 8 + 4 * e4 + i] * sc;
                const __hip_fp8_e4m3 f8(y);
                w |= ((unsigned int)f8.__x) << (8 * i);
            }
            dst32[u] = w;
        }
        __syncthreads();
    }
}

// ---------------------------------------------------------------------------
// Kernel 2 template: R13 structure, phase-ablated. All variants keep the tail.
// ---------------------------------------------------------------------------
template<int V>
__global__ __launch_bounds__(256, 4) void nnclr_mainT(const unsigned char* __restrict__ pq2,
                                                      float* __restrict__ sOut,
                                                      float* __restrict__ dOut)
{
    const int rb = blockIdx.x, ch = blockIdx.y, pair = blockIdx.z;
    const int pi = pair >> 1, pj = pair & 1;
    const int tid = threadIdx.x, lane = tid & 63, wave = tid >> 6;
    const int cl = lane & 31, hk = lane >> 5;
    const int b0 = rb * 32;

    __shared__ float sArr[4][32];
    __shared__ float dArr[4][32];

    const fp8x8* P = (const fp8x8*)pq2;
    frag32 aF[4];
    #pragma unroll
    for (int kb = 0; kb < 4; ++kb)
        #pragma unroll
        for (int q = 0; q < 4; ++q)
            aF[kb].g[q] = P[((pi * 64 + rb) * 32 + 8 * kb + 4 * hk + q) * 32 + cl];

    const int  rDiag    = (cl & 3) + 4 * (cl >> 3);
    const bool laneDiag = (((cl >> 2) & 1) == hk);
    const fp8x8* Bbase = P + (size_t)(2 + pj) * 64 * 32 * 32;
    const int cg0 = ch * 16 + wave * 4;

    // V2: load B fragments ONCE (outside rep/cgl loops)
    frag32 bfixed[4];
    if (V == 2) {
        #pragma unroll
        for (int kb = 0; kb < 4; ++kb)
            #pragma unroll
            for (int q = 0; q < 4; ++q)
                bfixed[kb].g[q] = Bbase[((size_t)cg0 * 32 + 8 * kb + 4 * hk + q) * 32 + cl];
    }

    for (int rep = 0; rep < REP_MAIN; ++rep) {
        asm volatile("" ::: "memory");
        float sAcc[16];
        #pragma unroll
        for (int r = 0; r < 16; ++r) sAcc[r] = 0.f;
        float d0 = 0.f;

        #pragma unroll (V == 4 ? 1 : 4)
        for (int cgl = 0; cgl < 4; ++cgl) {
            const int cg = cg0 + cgl;
            frag32 bf[4];
            if (V == 2) {
                #pragma unroll
                for (int kb = 0; kb < 4; ++kb) {
                    bf[kb] = bfixed[kb];
                    int tmp = bf[kb].v[0];
                    asm volatile("" : "+v"(tmp));   // defeat CSE across cgl/rep
                    bf[kb].v[0] = tmp;
                }
            } else {
                #pragma unroll
                for (int kb = 0; kb < 4; ++kb)
                    #pragma unroll
                    for (int q = 0; q < 4; ++q)
                        bf[kb].g[q] = Bbase[((size_t)cg * 32 + 8 * kb + 4 * hk + q) * 32 + cl];
            }
            f32x16 acc;
            #pragma unroll
            for (int r = 0; r < 16; ++r) acc[r] = 0.f;
            #pragma unroll
            for (int kb = 0; kb < 4; ++kb)
                acc = __builtin_amdgcn_mfma_scale_f32_32x32x64_f8f6f4(
                          aF[kb].v, bf[kb].v, acc, 0, 0, 0, SCALE1, 0, SCALE1);
            const bool diagCG = (cg == rb);
            #pragma unroll
            for (int r = 0; r < 16; ++r) {
                const float v0 = acc[r];
                if (V == 1) sAcc[r] += v0 - 5.0f;          // no-exp ablation
                else        sAcc[r] += __expf(v0 - 5.0f);
                if (diagCG) {
                    const bool m = laneDiag && (r == rDiag);
                    d0 += m ? v0 : 0.f;
                }
            }
        }

        #pragma unroll
        for (int r = 0; r < 16; ++r) {
            float s0 = sAcc[r];
            #pragma unroll
            for (int msk = 1; msk < 32; msk <<= 1) s0 += __shfl_xor(s0, msk, 64);
            sAcc[r] = s0;
        }
        if (cl == 0) {
            #pragma unroll
            for (int r = 0; r < 16; ++r) {
                const int rowl = (r & 3) + 8 * (r >> 2) + 4 * hk;
                sArr[wave][rowl] = sAcc[r];
            }
        }
        if (laneDiag) dArr[wave][cl] = d0;
        __syncthreads();
        if (tid < 32) {
            float s = 0.f, d = 0.f;
            #pragma unroll
            for (int w = 0; w < 4; ++w) { s += sArr[w][tid]; d += dArr[w][tid]; }
            const int b = b0 + tid;
            sOut[((size_t)pair * TB + b) * 4 + ch] = s;
            dOut[((size_t)pair * TB + b) * 4 + ch] = d;
        }
        __syncthreads();
    }
}

// ---------------------------------------------------------------------------
// Kernel 3: merged final (== R9/R10)
// ---------------------------------------------------------------------------
__global__ __launch_bounds__(1024) void nnclr_final(const float* __restrict__ sPart,
                                                    const float* __restrict__ dPart,
                                                    float* __restrict__ out) {
    const int tid = threadIdx.x;
    float acc[4] = {0.f, 0.f, 0.f, 0.f};
    #pragma unroll
    for (int k = 0; k < 8; ++k) {
        const int item = k * 1024 + tid;
        const float4 sv = ((const float4*)sPart)[item];
        const float4 dv = ((const float4*)dPart)[item];
        const float s = (sv.x + sv.y) + (sv.z + sv.w);
        const float d = (dv.x + dv.y) + (dv.z + dv.w);
        acc[k >> 1] += 5.0f + logf(s) - d;
    }
    __shared__ float red[16][4];
    const int lane = tid & 63, wave = tid >> 6;
    #pragma unroll
    for (int p = 0; p < 4; ++p) {
        #pragma unroll
        for (int m = 1; m < 64; m <<= 1) acc[p] += __shfl_xor(acc[p], m, 64);
    }
    if (lane == 0) {
        #pragma unroll
        for (int p = 0; p < 4; ++p) red[wave][p] = acc[p];
    }
    __syncthreads();
    if (tid == 0) {
        float L[4];
        #pragma unroll
        for (int p = 0; p < 4; ++p) {
            float a = 0.f;
            for (int w = 0; w < 16; ++w) a += red[w][p];
            L[p] = a / (float)TB;
        }
        const float gs = L[1] + L[2];
        const float ls = L[0] + L[1] + L[2] + L[3];
        out[0] = (gs + ls) / 6.0f;
        out[1] = gs * 0.5f;
        out[2] = ls * 0.25f;
    }
}

extern "C" void kernel_launch(void* const* d_in, const int* in_sizes, int n_in,
                              void* d_out, int out_size, void* d_ws, size_t ws_size,
                              hipStream_t stream) {
    const float* projected = (const float*)d_in[0];
    const float* predicted = (const float*)d_in[1];

    unsigned char* pq2 = (unsigned char*)d_ws;                          // 2 MB
    float* sPart = (float*)((char*)d_ws + 4u * 1024u * 1024u);          // 128 KB (real)
    float* dPart = sPart + (size_t)4 * TB * 4;                          // 128 KB (real)
    float* sScr  = dPart + (size_t)4 * TB * 4;                          // 128 KB (scratch)
    float* dScr  = sScr  + (size_t)4 * TB * 4;                          // 128 KB (scratch)
    float* out = (float*)d_out;

    dim3 gprep(64, 4);
    dim3 gmain(64, 4, 4);
    nnclr_prep<<<gprep, 256, 0, stream>>>(projected, predicted, pq2);
    nnclr_mainT<1><<<gmain, 256, 0, stream>>>(pq2, sScr, dScr);   // no-exp
    nnclr_mainT<2><<<gmain, 256, 0, stream>>>(pq2, sScr, dScr);   // no per-cgl loads
    nnclr_mainT<4><<<gmain, 256, 0, stream>>>(pq2, sScr, dScr);   // unroll 1
    nnclr_mainT<0><<<gmain, 256, 0, stream>>>(pq2, sPart, dPart); // full anchor (real)
    nnclr_final<<<1, 1024, 0, stream>>>(sPart, dPart, out);
}

// Round 18
// 27.350 us; speedup vs baseline: 21.2703x; 21.2703x over previous
//
#include <hip/hip_runtime.h>
#include <hip/hip_bf16.h>
#include <hip/hip_fp8.h>
#include <stdint.h>

// Problem constants (fixed by reference): B=2048, D=256, Vg=2, Vt=4 (only j<2 used), T=0.2
#define TB 2048
#define TD 256

typedef long long                                         fp8x8;   // 8 fp8 = 2 VGPR
typedef __attribute__((ext_vector_type(8)))  int          int8v;   // 32 fp8 = 8 VGPR
typedef __attribute__((ext_vector_type(16))) float        f32x16;

union frag32 { fp8x8 g[4]; int8v v; };   // 4 x 8B granules = one 32x32x64 operand

#define SQRT5 2.23606797749979f   // fold sqrt(1/T)=sqrt(5) into BOTH normalized operands
#define SCALE1 0x7F               // E8M0: 2^(127-127) = 1.0

// ---------------------------------------------------------------------------
// Kernel 1: normalize rows, scale by sqrt(5), cast fp8-e4m3 (OCP), write in
// MFMA fragment order: pq2[v][grp][g][col] of 8B granules. (== R10)
// Measured (R15, REP=32 never surfaced): <= 1.2 us standalone.
// ---------------------------------------------------------------------------
__global__ __launch_bounds__(256) void nnclr_prep(const float* __restrict__ proj,
                                                  const float* __restrict__ pred,
                                                  unsigned char* __restrict__ pq2) {
    const int grp = blockIdx.x;      // 0..63
    const int v   = blockIdx.y;      // 0..3
    const int t   = threadIdx.x;     // 0..255

    __shared__ float rowbuf[32][260];
    __shared__ float scales[32];

    #pragma unroll
    for (int it = 0; it < 8; ++it) {
        const int f = it * 256 + t;
        const int m = f >> 6, q = f & 63;
        const int b = grp * 32 + m;
        const float4* src = (v < 2) ? (const float4*)(proj + ((size_t)b * 2 + v) * TD)
                                    : (const float4*)(pred + ((size_t)b * 4 + (v - 2)) * TD);
        *(float4*)&rowbuf[m][q * 4] = src[q];
    }
    __syncthreads();
    {
        const int row = t >> 3, l8 = t & 7;
        float ss = 0.f;
        #pragma unroll
        for (int n = 0; n < 32; ++n) { const float y = rowbuf[row][l8 + 8 * n]; ss += y * y; }
        ss += __shfl_xor(ss, 1, 64);
        ss += __shfl_xor(ss, 2, 64);
        ss += __shfl_xor(ss, 4, 64);
        if (l8 == 0) scales[row] = SQRT5 / fmaxf(sqrtf(ss), 1e-12f);
    }
    __syncthreads();
    unsigned int* dst32 = (unsigned int*)(pq2 + (size_t)(v * 64 + grp) * 8192);
    #pragma unroll
    for (int it = 0; it < 8; ++it) {
        const int u   = it * 256 + t;
        const int m   = u >> 6;
        const int col = (u >> 1) & 31;
        const int e4  = u & 1;
        const float sc = scales[col];
        unsigned int w = 0;
        #pragma unroll
        for (int i = 0; i < 4; ++i) {
            const float y = rowbuf[col][m * 8 + 4 * e4 + i] * sc;
            const __hip_fp8_e4m3 f8(y);
            w |= ((unsigned int)f8.__x) << (8 * i);
        }
        dst32[u] = w;
    }
}

// ---------------------------------------------------------------------------
// Kernel 2: MX-scaled fp8 MFMA, one (i,j) pair per block, grid (64,4,4).
// R15 ablation verdict: (256,4) launch bound clamped VGPR to 64 against a
// ~100-110 live set -> ~56 MB/rep scratch spill traffic dominated runtime
// (V_no-exp == V_no-loads == V_unroll1 == V_full). Fix: (256,2) -> allocator
// targets 128 VGPR (R12 evidence), live set fits, ZERO spills. Grid still
// 1024 blocks = 16 waves/CU (grid-limited); 16 x 128 VGPR = full CU pool.
// ---------------------------------------------------------------------------
__global__ __launch_bounds__(256, 2) void nnclr_main(const unsigned char* __restrict__ pq2,
                                                     float* __restrict__ sPart,  // [4][2048][4]
                                                     float* __restrict__ dPart)  // [4][2048][4]
{
    const int rb = blockIdx.x, ch = blockIdx.y, pair = blockIdx.z;
    const int pi = pair >> 1, pj = pair & 1;
    const int tid = threadIdx.x, lane = tid & 63, wave = tid >> 6;
    const int cl = lane & 31, hk = lane >> 5;
    const int b0 = rb * 32;

    const fp8x8* P = (const fp8x8*)pq2;                 // granule-indexed (8B)
    frag32 aF[4];
    #pragma unroll
    for (int kb = 0; kb < 4; ++kb) {
        #pragma unroll
        for (int q = 0; q < 4; ++q)
            aF[kb].g[q] = P[((pi * 64 + rb) * 32 + 8 * kb + 4 * hk + q) * 32 + cl];
    }

    float sAcc[16];
    #pragma unroll
    for (int r = 0; r < 16; ++r) sAcc[r] = 0.f;
    float d0 = 0.f;
    // lane's diagonal slot: holds C[row=cl][col=cl] iff hk==(cl>>2)&1, at r=rDiag
    const int  rDiag    = (cl & 3) + 4 * (cl >> 3);
    const bool laneDiag = (((cl >> 2) & 1) == hk);

    const fp8x8* Bbase = P + (size_t)(2 + pj) * 64 * 32 * 32;
    const int cg0 = ch * 16 + wave * 4;                 // this wave's first col-group

    #pragma unroll
    for (int cgl = 0; cgl < 4; ++cgl) {
        const int cg = cg0 + cgl;
        frag32 bf[4];
        #pragma unroll
        for (int kb = 0; kb < 4; ++kb)
            #pragma unroll
            for (int q = 0; q < 4; ++q)
                bf[kb].g[q] = Bbase[((size_t)cg * 32 + 8 * kb + 4 * hk + q) * 32 + cl];
        f32x16 acc;
        #pragma unroll
        for (int r = 0; r < 16; ++r) acc[r] = 0.f;
        #pragma unroll
        for (int kb = 0; kb < 4; ++kb)
            acc = __builtin_amdgcn_mfma_scale_f32_32x32x64_f8f6f4(
                      aF[kb].v, bf[kb].v, acc, 0, 0, 0, SCALE1, 0, SCALE1);
        // epilogue: fixed-max (m=5) sum-of-exp + diag pick (static indexing)
        const bool diagCG = (cg == rb);                 // wave-uniform
        #pragma unroll
        for (int r = 0; r < 16; ++r) {
            const float v0 = acc[r];
            sAcc[r] += __expf(v0 - 5.0f);
            if (diagCG) {
                const bool m = laneDiag && (r == rDiag);
                d0 += m ? v0 : 0.f;
            }
        }
    }

    // per-row col-sum: reduce over the 32 lanes of each hk half
    #pragma unroll
    for (int r = 0; r < 16; ++r) {
        float s0 = sAcc[r];
        #pragma unroll
        for (int msk = 1; msk < 32; msk <<= 1) s0 += __shfl_xor(s0, msk, 64);
        sAcc[r] = s0;
    }

    __shared__ float sArr[4][32];
    __shared__ float dArr[4][32];
    if (cl == 0) {
        #pragma unroll
        for (int r = 0; r < 16; ++r) {
            const int rowl = (r & 3) + 8 * (r >> 2) + 4 * hk;
            sArr[wave][rowl] = sAcc[r];
        }
    }
    if (laneDiag) dArr[wave][cl] = d0;
    __syncthreads();
    if (tid < 32) {
        float s = 0.f, d = 0.f;
        #pragma unroll
        for (int w = 0; w < 4; ++w) { s += sArr[w][tid]; d += dArr[w][tid]; }
        const int b = b0 + tid;
        sPart[((size_t)pair * TB + b) * 4 + ch] = s;
        dPart[((size_t)pair * TB + b) * 4 + ch] = d;
    }
}

// ---------------------------------------------------------------------------
// Kernel 3 (merged): 1 block x 1024 thr. Per (pair,row): combine 4 chunks,
// L = 5 + ln(s) - d; block-reduce per pair; thread 0 -> 3 outputs.
// Measured (R12, REP=16 never surfaced): <= 2.5 us standalone.
// ---------------------------------------------------------------------------
__global__ __launch_bounds__(1024) void nnclr_final(const float* __restrict__ sPart,
                                                    const float* __restrict__ dPart,
                                                    float* __restrict__ out) {
    const int tid = threadIdx.x;
    float acc[4] = {0.f, 0.f, 0.f, 0.f};
    #pragma unroll
    for (int k = 0; k < 8; ++k) {
        const int item = k * 1024 + tid;                // pair*2048 + row ; pair = k>>1
        const float4 sv = ((const float4*)sPart)[item];
        const float4 dv = ((const float4*)dPart)[item];
        const float s = (sv.x + sv.y) + (sv.z + sv.w);
        const float d = (dv.x + dv.y) + (dv.z + dv.w);
        acc[k >> 1] += 5.0f + logf(s) - d;
    }
    __shared__ float red[16][4];
    const int lane = tid & 63, wave = tid >> 6;
    #pragma unroll
    for (int p = 0; p < 4; ++p) {
        #pragma unroll
        for (int m = 1; m < 64; m <<= 1) acc[p] += __shfl_xor(acc[p], m, 64);
    }
    if (lane == 0) {
        #pragma unroll
        for (int p = 0; p < 4; ++p) red[wave][p] = acc[p];
    }
    __syncthreads();
    if (tid == 0) {
        float L[4];
        #pragma unroll
        for (int p = 0; p < 4; ++p) {
            float a = 0.f;
            for (int w = 0; w < 16; ++w) a += red[w][p];
            L[p] = a / (float)TB;         // mean over b
        }
        const float gs = L[1] + L[2];                 // L[0][1] + L[1][0]
        const float ls = L[0] + L[1] + L[2] + L[3];   // all four (Vl==Vg==2)
        out[0] = (gs + ls) / 6.0f;        // total
        out[1] = gs * 0.5f;               // global_loss
        out[2] = ls * 0.25f;              // local_loss
    }
}

extern "C" void kernel_launch(void* const* d_in, const int* in_sizes, int n_in,
                              void* d_out, int out_size, void* d_ws, size_t ws_size,
                              hipStream_t stream) {
    const float* projected = (const float*)d_in[0];   // [2048][2][256] f32
    const float* predicted = (const float*)d_in[1];   // [2048][4][256] f32

    unsigned char* pq2 = (unsigned char*)d_ws;                          // 2 MB fp8, fragment-ordered
    float* sPart = (float*)((char*)d_ws + 4u * 1024u * 1024u);          // 128 KB
    float* dPart = sPart + (size_t)4 * TB * 4;                          // 128 KB
    float* out = (float*)d_out;

    dim3 gprep(64, 4);
    nnclr_prep<<<gprep, 256, 0, stream>>>(projected, predicted, pq2);
    dim3 gmain(64, 4, 4);
    nnclr_main<<<gmain, 256, 0, stream>>>(pq2, sPart, dPart);
    nnclr_final<<<1, 1024, 0, stream>>>(sPart, dPart, out);
}